// Round 5
// baseline (247.844 us; speedup 1.0000x reference)
//
#include <hip/hip_runtime.h>
#include <math.h>

#define B_ 2
#define S_ 2048
#define E_ 1024
#define H_ 16
#define D_ 64

typedef __attribute__((ext_vector_type(8))) short short8;
typedef __attribute__((ext_vector_type(4))) float f32x4;
typedef __attribute__((ext_vector_type(4))) unsigned short us4;
typedef __attribute__((ext_vector_type(8))) unsigned short us8;
typedef unsigned short ushort_t;

#define MFMA16 __builtin_amdgcn_mfma_f32_16x16x32_bf16

__device__ __forceinline__ ushort_t f2bf(float f) {
    unsigned int u = __float_as_uint(f);
    u += 0x7FFFu + ((u >> 16) & 1u);
    return (ushort_t)(u >> 16);
}
__device__ __forceinline__ float bf2f(ushort_t h) {
    return __uint_as_float((unsigned int)h << 16);
}

// async global->LDS, 16B per lane; LDS dest = wave-uniform base + lane*16
__device__ __forceinline__ void gload16(const void* g, void* l) {
    __builtin_amdgcn_global_load_lds(
        (__attribute__((address_space(1))) void*)(unsigned long long)g,
        (__attribute__((address_space(3))) void*)(unsigned int)(unsigned long long)l,
        16, 0, 0);
}

// ---------------- x -> (hi, lo) bf16 split ----------------
__global__ __launch_bounds__(256)
void split_x(const float* __restrict__ in, ushort_t* __restrict__ hi,
             ushort_t* __restrict__ lo)
{
    const size_t base = ((size_t)blockIdx.x * 256 + threadIdx.x) * 8;
    float v[8];
    *reinterpret_cast<float4*>(&v[0]) = *reinterpret_cast<const float4*>(&in[base]);
    *reinterpret_cast<float4*>(&v[4]) = *reinterpret_cast<const float4*>(&in[base + 4]);
    us8 h, l;
#pragma unroll
    for (int j = 0; j < 8; ++j) {
        ushort_t hh = f2bf(v[j]);
        h[j] = hh;
        l[j] = f2bf(v[j] - bf2f(hh));
    }
    *reinterpret_cast<us8*>(&hi[base]) = h;
    *reinterpret_cast<us8*>(&lo[base]) = l;
}

// ---------------- W[k][n] -> Wt[z][n][k] hi/lo bf16 (transpose + split) ----------------
__global__ __launch_bounds__(256)
void wsplit_t(const float* __restrict__ Wq, const float* __restrict__ Wk,
              const float* __restrict__ Wv, const float* __restrict__ Wo,
              ushort_t* __restrict__ Wth, ushort_t* __restrict__ Wtl)
{
    __shared__ float T[64][65];
    const int tid = threadIdx.x;
    const int z = blockIdx.z;
    const float* W = (z == 0) ? Wq : (z == 1) ? Wk : (z == 2) ? Wv : Wo;
    const int kt = blockIdx.y * 64;
    const int nt = blockIdx.x * 64;

    const int lr = (tid >> 4) * 4;
    const int lc = (tid & 15) * 4;
#pragma unroll
    for (int i = 0; i < 4; ++i) {
        float4 v = *reinterpret_cast<const float4*>(&W[(size_t)(kt + lr + i) * 1024 + nt + lc]);
        T[lr + i][lc + 0] = v.x; T[lr + i][lc + 1] = v.y;
        T[lr + i][lc + 2] = v.z; T[lr + i][lc + 3] = v.w;
    }
    __syncthreads();

    const int n = tid >> 2;
    const int kc = (tid & 3) * 16;
    us8 h[2], l[2];
#pragma unroll
    for (int u = 0; u < 2; ++u)
#pragma unroll
        for (int j = 0; j < 8; ++j) {
            float v = T[kc + u * 8 + j][n];
            ushort_t hh = f2bf(v);
            h[u][j] = hh;
            l[u][j] = f2bf(v - bf2f(hh));
        }
    ushort_t* dh = Wth + ((size_t)z * 1024 + nt + n) * 1024 + kt + kc;
    ushort_t* dl = Wtl + ((size_t)z * 1024 + nt + n) * 1024 + kt + kc;
    *reinterpret_cast<us8*>(dh)     = h[0];
    *reinterpret_cast<us8*>(dh + 8) = h[1];
    *reinterpret_cast<us8*>(dl)     = l[0];
    *reinterpret_cast<us8*>(dl + 8) = l[1];
}

// ================= 256x256 8-phase bf16x3 QKV GEMM =================
// 512 threads = 8 waves (2M x 4N), BK=32, dbuf LDS 128 KB, 4 streams
// (Ah,Al,Bh,Bl). Per K-step: 4 phases x 24 MFMA; stage tile t+1 issued in
// phase 0, vmcnt(0) drained only at phase 3 (loads in flight across
// 3 phase-barrier pairs). XOR-involution swizzle on source & read (T2).
__global__ __launch_bounds__(512, 2)
void gemm_qkv_8p(const ushort_t* __restrict__ xh, const ushort_t* __restrict__ xl,
                 const ushort_t* __restrict__ Wth, const ushort_t* __restrict__ Wtl,
                 const float* __restrict__ bq, const float* __restrict__ bk,
                 const float* __restrict__ bv,
                 ushort_t* __restrict__ Qb, ushort_t* __restrict__ Kb,
                 ushort_t* __restrict__ Vb, float qalpha)
{
    __shared__ ushort_t lds[2][4][256 * 32];   // 128 KB

    const int tid  = threadIdx.x;
    const int lane = tid & 63;
    const int w    = tid >> 6;         // 0..7
    const int l15  = lane & 15;
    const int g    = lane >> 4;
    const int wr   = w >> 2;           // 0..1
    const int wc   = w & 3;            // 0..3

    // bijective XCD swizzle (192 = 8 * 24)
    int bid = (int)blockIdx.x;
    bid = (bid & 7) * 24 + (bid >> 3);
    const int which = bid / 64;
    const int rem   = bid % 64;
    const int m0 = (rem >> 2) * 256;
    const int n0 = (rem & 3) * 256;

    const ushort_t* Ah_ = xh;
    const ushort_t* Al_ = xl;
    const ushort_t* Bh_ = Wth + (size_t)which * 1024 * 1024;
    const ushort_t* Bl_ = Wtl + (size_t)which * 1024 * 1024;
    const float* bias = (which == 0) ? bq : (which == 1) ? bk : bv;
    ushort_t* out = (which == 0) ? Qb : (which == 1) ? Kb : Vb;
    const float alpha = (which == 0) ? qalpha : 1.0f;

    // staging: wave w stages j-blocks {2w, 2w+1} of each stream
    const int sr  = lane >> 2;                        // row in 16-row j-block
    const int scz = (lane & 3) ^ ((sr >> 1) & 3);     // swizzled source chunk
    const int jb0 = w * 2, jb1 = jb0 + 1;
    const unsigned int offA0 = (unsigned int)(m0 + jb0 * 16 + sr) * 1024u + scz * 8;
    const unsigned int offA1 = (unsigned int)(m0 + jb1 * 16 + sr) * 1024u + scz * 8;
    const unsigned int offB0 = (unsigned int)(n0 + jb0 * 16 + sr) * 1024u + scz * 8;
    const unsigned int offB1 = (unsigned int)(n0 + jb1 * 16 + sr) * 1024u + scz * 8;

    // read-side swizzle constants
    const int sx  = (l15 >> 1) & 3;
    const int rd1 = (((g >> 1) + 0) ^ sx) * 8 + (g & 1) * 4;
    const int rd2 = (((g >> 1) + 2) ^ sx) * 8 + (g & 1) * 4;

#define STAGEQ(bufi, kts)                                                     \
    { const unsigned int k0s = (unsigned int)(kts) * 32u;                     \
      gload16(Ah_ + offA0 + k0s, &lds[bufi][0][jb0 * 512]);                   \
      gload16(Ah_ + offA1 + k0s, &lds[bufi][0][jb1 * 512]);                   \
      gload16(Al_ + offA0 + k0s, &lds[bufi][1][jb0 * 512]);                   \
      gload16(Al_ + offA1 + k0s, &lds[bufi][1][jb1 * 512]);                   \
      gload16(Bh_ + offB0 + k0s, &lds[bufi][2][jb0 * 512]);                   \
      gload16(Bh_ + offB1 + k0s, &lds[bufi][2][jb1 * 512]);                   \
      gload16(Bl_ + offB0 + k0s, &lds[bufi][3][jb0 * 512]);                   \
      gload16(Bl_ + offB1 + k0s, &lds[bufi][3][jb1 * 512]); }

    f32x4 acc[8][4];
#pragma unroll
    for (int i = 0; i < 8; ++i)
#pragma unroll
        for (int j = 0; j < 4; ++j) { acc[i][j][0] = 0.f; acc[i][j][1] = 0.f; acc[i][j][2] = 0.f; acc[i][j][3] = 0.f; }

    // prologue: stage tile 0 into buf 0
    STAGEQ(0, 0);
    asm volatile("s_waitcnt vmcnt(0)" ::: "memory");
    __builtin_amdgcn_s_barrier();

    for (int kt = 0; kt < 32; ++kt) {
        const int cur = kt & 1;
        const ushort_t* AsHc = lds[cur][0];
        const ushort_t* AsLc = lds[cur][1];
        const ushort_t* BsHc = lds[cur][2];
        const ushort_t* BsLc = lds[cur][3];

        short8 bh[4], bl[4];
#pragma unroll
        for (int p = 0; p < 4; ++p) {
            if (p == 0) {
#pragma unroll
                for (int nb = 0; nb < 4; ++nb) {
                    const int rb = (wc * 64 + nb * 16 + l15) * 32;
                    union { us4 h[2]; short8 s; } u;
                    u.h[0] = *reinterpret_cast<const us4*>(BsHc + rb + rd1);
                    u.h[1] = *reinterpret_cast<const us4*>(BsHc + rb + rd2);
                    bh[nb] = u.s;
                    union { us4 h[2]; short8 s; } v;
                    v.h[0] = *reinterpret_cast<const us4*>(BsLc + rb + rd1);
                    v.h[1] = *reinterpret_cast<const us4*>(BsLc + rb + rd2);
                    bl[nb] = v.s;
                }
            }
            const int mbA = 2 * p, mbB = 2 * p + 1;
            const int rbA = (wr * 128 + mbA * 16 + l15) * 32;
            const int rbB = (wr * 128 + mbB * 16 + l15) * 32;
            union { us4 h[2]; short8 s; } uah, ual, ubh, ubl;
            uah.h[0] = *reinterpret_cast<const us4*>(AsHc + rbA + rd1);
            uah.h[1] = *reinterpret_cast<const us4*>(AsHc + rbA + rd2);
            ual.h[0] = *reinterpret_cast<const us4*>(AsLc + rbA + rd1);
            ual.h[1] = *reinterpret_cast<const us4*>(AsLc + rbA + rd2);
            ubh.h[0] = *reinterpret_cast<const us4*>(AsHc + rbB + rd1);
            ubh.h[1] = *reinterpret_cast<const us4*>(AsHc + rbB + rd2);
            ubl.h[0] = *reinterpret_cast<const us4*>(AsLc + rbB + rd1);
            ubl.h[1] = *reinterpret_cast<const us4*>(AsLc + rbB + rd2);
            const short8 ah0 = uah.s, al0 = ual.s, ah1 = ubh.s, al1 = ubl.s;

            if (p == 0 && kt + 1 < 32) { STAGEQ(cur ^ 1, kt + 1); }

            __builtin_amdgcn_s_barrier();
            asm volatile("s_waitcnt lgkmcnt(0)" ::: "memory");
            __builtin_amdgcn_s_setprio(1);
#pragma unroll
            for (int nb = 0; nb < 4; ++nb) {
                acc[mbA][nb] = MFMA16(ah0, bh[nb], acc[mbA][nb], 0, 0, 0);
                acc[mbA][nb] = MFMA16(al0, bh[nb], acc[mbA][nb], 0, 0, 0);
                acc[mbA][nb] = MFMA16(ah0, bl[nb], acc[mbA][nb], 0, 0, 0);
                acc[mbB][nb] = MFMA16(ah1, bh[nb], acc[mbB][nb], 0, 0, 0);
                acc[mbB][nb] = MFMA16(al1, bh[nb], acc[mbB][nb], 0, 0, 0);
                acc[mbB][nb] = MFMA16(ah1, bl[nb], acc[mbB][nb], 0, 0, 0);
            }
            __builtin_amdgcn_s_setprio(0);
            if (p == 3) { asm volatile("s_waitcnt vmcnt(0)" ::: "memory"); }
            __builtin_amdgcn_s_barrier();
        }
    }
#undef STAGEQ

    // epilogue: bias + alpha, bf16 out
    float bvv[4];
#pragma unroll
    for (int nb = 0; nb < 4; ++nb) bvv[nb] = bias[n0 + wc * 64 + nb * 16 + l15];
#pragma unroll
    for (int mb = 0; mb < 8; ++mb)
#pragma unroll
        for (int r = 0; r < 4; ++r) {
            const size_t row = m0 + wr * 128 + mb * 16 + 4 * g + r;
#pragma unroll
            for (int nb = 0; nb < 4; ++nb) {
                const float vv = (acc[mb][nb][r] + bvv[nb]) * alpha;
                out[row * 1024 + n0 + wc * 64 + nb * 16 + l15] = f2bf(vv);
            }
        }
}

// ---------------- bf16x3 MFMA GEMM core: 128x128 tile (for gemm_o) ----------------
__device__ __forceinline__ void gemm128_core(
    const ushort_t* __restrict__ Ah, const ushort_t* __restrict__ Al,
    const ushort_t* __restrict__ Bh, const ushort_t* __restrict__ Bl,
    int m0, int n0,
    ushort_t* AsH, ushort_t* AsL, ushort_t* BsH, ushort_t* BsL,
    f32x4 acc[4][4])
{
    const int tid  = threadIdx.x;
    const int lane = tid & 63;
    const int w    = tid >> 6;
    const int l15  = lane & 15;
    const int g    = lane >> 4;
    const int wr   = w >> 1;
    const int wc   = w & 1;

    const int sr  = lane >> 2;
    const int scz = (lane & 3) ^ ((sr >> 1) & 3);
    const int sc  = scz * 8;
    const int j0 = w * 2, j1 = j0 + 1;

    const ushort_t* gAh0 = Ah + (size_t)(m0 + j0 * 16 + sr) * 1024 + sc;
    const ushort_t* gAh1 = Ah + (size_t)(m0 + j1 * 16 + sr) * 1024 + sc;
    const ushort_t* gAl0 = Al + (size_t)(m0 + j0 * 16 + sr) * 1024 + sc;
    const ushort_t* gAl1 = Al + (size_t)(m0 + j1 * 16 + sr) * 1024 + sc;
    const ushort_t* gBh0 = Bh + (size_t)(n0 + j0 * 16 + sr) * 1024 + sc;
    const ushort_t* gBh1 = Bh + (size_t)(n0 + j1 * 16 + sr) * 1024 + sc;
    const ushort_t* gBl0 = Bl + (size_t)(n0 + j0 * 16 + sr) * 1024 + sc;
    const ushort_t* gBl1 = Bl + (size_t)(n0 + j1 * 16 + sr) * 1024 + sc;

    const int sx  = (l15 >> 1) & 3;
    const int c1s = ((g >> 1) + 0) ^ sx;
    const int c2s = ((g >> 1) + 2) ^ sx;
    const int o1  = (g & 1) * 4;
    const int rd1 = c1s * 8 + o1;
    const int rd2 = c2s * 8 + o1;

    for (int kt = 0; kt < 32; ++kt) {
        const int k0 = kt * 32;
        if (kt) __syncthreads();
        gload16(gAh0 + k0, AsH + j0 * 512);
        gload16(gAh1 + k0, AsH + j1 * 512);
        gload16(gAl0 + k0, AsL + j0 * 512);
        gload16(gAl1 + k0, AsL + j1 * 512);
        gload16(gBh0 + k0, BsH + j0 * 512);
        gload16(gBh1 + k0, BsH + j1 * 512);
        gload16(gBl0 + k0, BsL + j0 * 512);
        gload16(gBl1 + k0, BsL + j1 * 512);
        asm volatile("s_waitcnt vmcnt(0)" ::: "memory");
        __syncthreads();

        short8 bh[4], bl[4];
#pragma unroll
        for (int nb = 0; nb < 4; ++nb) {
            const int rbase = (wc * 64 + nb * 16 + l15) * 32;
            union { us4 h[2]; short8 s; } u;
            u.h[0] = *reinterpret_cast<const us4*>(BsH + rbase + rd1);
            u.h[1] = *reinterpret_cast<const us4*>(BsH + rbase + rd2);
            bh[nb] = u.s;
            union { us4 h[2]; short8 s; } v;
            v.h[0] = *reinterpret_cast<const us4*>(BsL + rbase + rd1);
            v.h[1] = *reinterpret_cast<const us4*>(BsL + rbase + rd2);
            bl[nb] = v.s;
        }
#pragma unroll
        for (int mb = 0; mb < 4; ++mb) {
            const int rbase = (wr * 64 + mb * 16 + l15) * 32;
            union { us4 h[2]; short8 s; } ua;
            ua.h[0] = *reinterpret_cast<const us4*>(AsH + rbase + rd1);
            ua.h[1] = *reinterpret_cast<const us4*>(AsH + rbase + rd2);
            union { us4 h[2]; short8 s; } ul;
            ul.h[0] = *reinterpret_cast<const us4*>(AsL + rbase + rd1);
            ul.h[1] = *reinterpret_cast<const us4*>(AsL + rbase + rd2);
            const short8 ah = ua.s, al = ul.s;
#pragma unroll
            for (int nb = 0; nb < 4; ++nb) {
                acc[mb][nb] = MFMA16(ah, bh[nb], acc[mb][nb], 0, 0, 0);
                acc[mb][nb] = MFMA16(al, bh[nb], acc[mb][nb], 0, 0, 0);
                acc[mb][nb] = MFMA16(ah, bl[nb], acc[mb][nb], 0, 0, 0);
            }
        }
    }
}

// ---------------- output GEMM (fp32 out) ----------------
__global__ __launch_bounds__(256, 3)
void gemm_o(const ushort_t* __restrict__ Ah, const ushort_t* __restrict__ Al,
            const ushort_t* __restrict__ Bh, const ushort_t* __restrict__ Bl,
            const float* __restrict__ bias, float* __restrict__ out)
{
    __shared__ ushort_t AsH[128 * 32], AsL[128 * 32], BsH[128 * 32], BsL[128 * 32];
    const int n0 = blockIdx.x * 128;
    const int m0 = blockIdx.y * 128;

    f32x4 acc[4][4];
#pragma unroll
    for (int i = 0; i < 4; ++i)
#pragma unroll
        for (int j = 0; j < 4; ++j) { acc[i][j][0] = 0.f; acc[i][j][1] = 0.f; acc[i][j][2] = 0.f; acc[i][j][3] = 0.f; }

    gemm128_core(Ah, Al, Bh, Bl, m0, n0, AsH, AsL, BsH, BsL, acc);

    const int tid = threadIdx.x;
    const int lane = tid & 63, l15 = lane & 15, g = lane >> 4;
    const int w = tid >> 6, wr = w >> 1, wc = w & 1;
    float bvv[4];
#pragma unroll
    for (int nb = 0; nb < 4; ++nb) bvv[nb] = bias[n0 + wc * 64 + nb * 16 + l15];
#pragma unroll
    for (int mb = 0; mb < 4; ++mb)
#pragma unroll
        for (int r = 0; r < 4; ++r) {
            const size_t row = m0 + wr * 64 + mb * 16 + 4 * g + r;
#pragma unroll
            for (int nb = 0; nb < 4; ++nb)
                out[row * 1024 + n0 + wc * 64 + nb * 16 + l15] = acc[mb][nb][r] + bvv[nb];
        }
}

// ---------------- MFMA bf16 flash attention (round-2 verified core) ----------------
__global__ __launch_bounds__(256, 2)
void attn_mfma(const ushort_t* __restrict__ Q, const ushort_t* __restrict__ K,
               const ushort_t* __restrict__ V, ushort_t* __restrict__ XHh,
               ushort_t* __restrict__ XHl)
{
    __shared__ __align__(16) ushort_t Kf[4 * 2 * 64 * 8];
    __shared__ __align__(16) ushort_t Vf[4 * 2 * 64 * 8];

    const int tid  = threadIdx.x;
    const int w    = tid >> 6;
    const int lane = tid & 63;
    const int l15  = lane & 15;
    const int g    = lane >> 4;

    const int qb = blockIdx.x;
    const int bh = blockIdx.y;
    const int b  = bh >> 4;
    const int hh = bh & 15;
    const size_t hoff = (size_t)b * S_ * E_ + (size_t)hh * S_ * D_;
    const ushort_t* Qh = Q + hoff;
    const ushort_t* Kh = K + hoff;
    const ushort_t* Vh = V + hoff;

    const int qw = qb * 128 + w * 32;

    short8 qf[2][2];
#pragma unroll
    for (int qg = 0; qg < 2; ++qg)
#pragma unroll
        for (int m = 0; m < 2; ++m) {
            const ushort_t* src = &Qh[(size_t)(qw + 16 * qg + l15) * D_ + 32 * m + 4 * g];
            us4 lo = *reinterpret_cast<const us4*>(src);
            us4 hi = *reinterpret_cast<const us4*>(src + 16);
            union { us4 h[2]; short8 s; } u;
            u.h[0] = lo; u.h[1] = hi;
            qf[qg][m] = u.s;
        }

    const int kr  = tid >> 2;
    const int kc0 = tid & 3;
    const int kkc = tid >> 4;
    const int vdc = tid & 15;
    const int vmc = kkc >> 3;
    const int vh  = (kkc >> 2) & 1;
    const int vg  = kkc & 3;
    const int vn  = vdc >> 2;

    f32x4 o[2][4];
#pragma unroll
    for (int qg = 0; qg < 2; ++qg)
#pragma unroll
        for (int n = 0; n < 4; ++n)
#pragma unroll
            for (int r = 0; r < 4; ++r) o[qg][n][r] = 0.f;

    float mrun[2] = {-1e30f, -1e30f};
    float lrun[2] = {0.f, 0.f};

    for (int kt = 0; kt < S_ / 64; ++kt) {
        us8 kreg[2];
#pragma unroll
        for (int u = 0; u < 2; ++u) {
            const int c8 = kc0 + 4 * u;
            kreg[u] = *reinterpret_cast<const us8*>(&Kh[(size_t)(kt * 64 + kr) * D_ + 8 * c8]);
        }
        us4 vreg[4];
#pragma unroll
        for (int i = 0; i < 4; ++i)
            vreg[i] = *reinterpret_cast<const us4*>(&Vh[(size_t)(kt * 64 + 4 * kkc + i) * D_ + 4 * vdc]);

        __syncthreads();

#pragma unroll
        for (int u = 0; u < 2; ++u) {
            const int c8 = kc0 + 4 * u;
            const int m = c8 >> 2;
            const int h = (c8 >> 1) & 1;
#pragma unroll
            for (int jh = 0; jh < 2; ++jh) {
                const int gk = (2 * c8 + jh) & 3;
                const int slot = gk * 16 + (kr & 15);
                us4 val;
#pragma unroll
                for (int i = 0; i < 4; ++i) val[i] = (ushort_t)kreg[u][4 * jh + i];
                *reinterpret_cast<us4*>(&Kf[((((kr >> 4) * 2 + m) * 64 + slot) * 8) + h * 4]) = val;
            }
        }
#pragma unroll
        for (int jj = 0; jj < 4; ++jj) {
            us4 val;
#pragma unroll
            for (int i = 0; i < 4; ++i) val[i] = vreg[i][jj];
            const int slot = vg * 16 + 4 * (vdc & 3) + jj;
            *reinterpret_cast<us4*>(&Vf[(((vn * 2 + vmc) * 64 + slot) * 8) + vh * 4]) = val;
        }
        __syncthreads();

        short8 kf[4][2];
#pragma unroll
        for (int kkb = 0; kkb < 4; ++kkb)
#pragma unroll
            for (int m = 0; m < 2; ++m)
                kf[kkb][m] = *reinterpret_cast<const short8*>(&Kf[((kkb * 2 + m) * 64 + lane) * 8]);

        f32x4 s[2][4];
#pragma unroll
        for (int qg = 0; qg < 2; ++qg)
#pragma unroll
            for (int kkb = 0; kkb < 4; ++kkb) {
                f32x4 z; z[0] = 0.f; z[1] = 0.f; z[2] = 0.f; z[3] = 0.f;
                z = MFMA16(kf[kkb][0], qf[qg][0], z, 0, 0, 0);
                s[qg][kkb] = MFMA16(kf[kkb][1], qf[qg][1], z, 0, 0, 0);
            }

        short8 vf[4][2];
#pragma unroll
        for (int n = 0; n < 4; ++n)
#pragma unroll
            for (int m = 0; m < 2; ++m)
                vf[n][m] = *reinterpret_cast<const short8*>(&Vf[((n * 2 + m) * 64 + lane) * 8]);

#pragma unroll
        for (int qg = 0; qg < 2; ++qg) {
            float t = s[qg][0][0];
#pragma unroll
            for (int kkb = 0; kkb < 4; ++kkb)
#pragma unroll
                for (int r = 0; r < 4; ++r) t = fmaxf(t, s[qg][kkb][r]);
            t = fmaxf(t, __shfl_xor(t, 16));
            t = fmaxf(t, __shfl_xor(t, 32));
            const float mnew = fmaxf(mrun[qg], t);
            const float corr = __builtin_amdgcn_exp2f(mrun[qg] - mnew);

            float rs = 0.f;
#pragma unroll
            for (int kkb = 0; kkb < 4; ++kkb)
#pragma unroll
                for (int r = 0; r < 4; ++r) {
                    const float p = __builtin_amdgcn_exp2f(s[qg][kkb][r] - mnew);
                    s[qg][kkb][r] = p;
                    rs += p;
                }
            rs += __shfl_xor(rs, 16);
            rs += __shfl_xor(rs, 32);
            lrun[qg] = lrun[qg] * corr + rs;
            mrun[qg] = mnew;

#pragma unroll
            for (int r = 0; r < 4; ++r) {
                const float c4 = __shfl(corr, 4 * g + r);
#pragma unroll
                for (int n = 0; n < 4; ++n) o[qg][n][r] *= c4;
            }

            short8 pa[2];
#pragma unroll
            for (int m = 0; m < 2; ++m) {
                us8 tmp;
#pragma unroll
                for (int r = 0; r < 4; ++r) {
                    tmp[r]     = f2bf(s[qg][2 * m][r]);
                    tmp[r + 4] = f2bf(s[qg][2 * m + 1][r]);
                }
                union { us8 u8; short8 s8; } cvt; cvt.u8 = tmp;
                pa[m] = cvt.s8;
            }
#pragma unroll
            for (int n = 0; n < 4; ++n) {
                o[qg][n] = MFMA16(pa[0], vf[n][0], o[qg][n], 0, 0, 0);
                o[qg][n] = MFMA16(pa[1], vf[n][1], o[qg][n], 0, 0, 0);
            }
        }
    }

#pragma unroll
    for (int qg = 0; qg < 2; ++qg) {
        const float invl = 1.f / lrun[qg];
#pragma unroll
        for (int r = 0; r < 4; ++r) {
            const float iv = __shfl(invl, 4 * g + r);
            const int row = qw + 16 * qg + 4 * g + r;
            const size_t base = ((size_t)b * S_ + row) * E_ + hh * D_ + l15;
#pragma unroll
            for (int n = 0; n < 4; ++n) {
                const float vv = o[qg][n][r] * iv;
                const ushort_t hi = f2bf(vv);
                XHh[base + 16 * n] = hi;
                XHl[base + 16 * n] = f2bf(vv - bf2f(hi));
            }
        }
    }
}

extern "C" void kernel_launch(void* const* d_in, const int* in_sizes, int n_in,
                              void* d_out, int out_size, void* d_ws, size_t ws_size,
                              hipStream_t stream) {
    (void)in_sizes; (void)n_in; (void)out_size; (void)ws_size;
    const float* x  = (const float*)d_in[0];
    const float* Wq = (const float*)d_in[1];
    const float* bq = (const float*)d_in[2];
    const float* Wk = (const float*)d_in[3];
    const float* bk = (const float*)d_in[4];
    const float* Wv = (const float*)d_in[5];
    const float* bv = (const float*)d_in[6];
    const float* Wo = (const float*)d_in[7];
    const float* bo = (const float*)d_in[8];
    float* out = (float*)d_out;

    char* ws = (char*)d_ws;
    const size_t MB8 = 8ull * 1024 * 1024;
    ushort_t* xhi = (ushort_t*)(ws);             // 8 MB, reused as XHh after QKV
    ushort_t* xlo = (ushort_t*)(ws + MB8);       // 8 MB, reused as XHl
    ushort_t* Wth = (ushort_t*)(ws + 2 * MB8);   // 8 MB  [4][1024][1024]
    ushort_t* Wtl = (ushort_t*)(ws + 3 * MB8);   // 8 MB
    ushort_t* Qb  = (ushort_t*)(ws + 4 * MB8);   // 8 MB
    ushort_t* Kb  = (ushort_t*)(ws + 5 * MB8);   // 8 MB
    ushort_t* Vb  = (ushort_t*)(ws + 6 * MB8);   // 8 MB  (total 56 MB)
    ushort_t* XHh = xhi;
    ushort_t* XHl = xlo;

    const float qalpha = 0.125f * 1.4426950408889634f;  // 1/sqrt(D) * log2(e)

    split_x<<<dim3(2048), dim3(256), 0, stream>>>(x, xhi, xlo);
    wsplit_t<<<dim3(16, 16, 4), dim3(256), 0, stream>>>(Wq, Wk, Wv, Wo, Wth, Wtl);

    gemm_qkv_8p<<<dim3(192), dim3(512), 0, stream>>>(xhi, xlo, Wth, Wtl,
                                                     bq, bk, bv, Qb, Kb, Vb, qalpha);

    attn_mfma<<<dim3(16, 32), dim3(256), 0, stream>>>(Qb, Kb, Vb, XHh, XHl);

    gemm_o<<<dim3(8, 32), dim3(256), 0, stream>>>(XHh, XHl,
                                                  Wth + 3ull * 1024 * 1024,
                                                  Wtl + 3ull * 1024 * 1024,
                                                  bo, out);
}

// Round 7
// 166.341 us; speedup vs baseline: 1.4900x; 1.4900x over previous
//
#include <hip/hip_runtime.h>
#include <math.h>

#define B_ 2
#define S_ 2048
#define E_ 1024
#define H_ 16
#define D_ 64

typedef __attribute__((ext_vector_type(8))) short short8;
typedef __attribute__((ext_vector_type(4))) float f32x4;
typedef __attribute__((ext_vector_type(4))) unsigned short us4;
typedef __attribute__((ext_vector_type(8))) unsigned short us8;
typedef unsigned short ushort_t;

#define MFMA16 __builtin_amdgcn_mfma_f32_16x16x32_bf16

__device__ __forceinline__ ushort_t f2bf(float f) {
    unsigned int u = __float_as_uint(f);
    u += 0x7FFFu + ((u >> 16) & 1u);
    return (ushort_t)(u >> 16);
}
__device__ __forceinline__ float bf2f(ushort_t h) {
    return __uint_as_float((unsigned int)h << 16);
}

// async global->LDS, 16B per lane; LDS dest = wave-uniform base + lane*16
__device__ __forceinline__ void gload16(const void* g, void* l) {
    __builtin_amdgcn_global_load_lds(
        (__attribute__((address_space(1))) void*)(unsigned long long)g,
        (__attribute__((address_space(3))) void*)(unsigned int)(unsigned long long)l,
        16, 0, 0);
}

// ---------------- x -> hi bf16 (QKV GEMM is plain bf16) ----------------
__global__ __launch_bounds__(256)
void split_x(const float* __restrict__ in, ushort_t* __restrict__ hi)
{
    const size_t base = ((size_t)blockIdx.x * 256 + threadIdx.x) * 8;
    float v[8];
    *reinterpret_cast<float4*>(&v[0]) = *reinterpret_cast<const float4*>(&in[base]);
    *reinterpret_cast<float4*>(&v[4]) = *reinterpret_cast<const float4*>(&in[base + 4]);
    us8 h;
#pragma unroll
    for (int j = 0; j < 8; ++j) h[j] = f2bf(v[j]);
    *reinterpret_cast<us8*>(&hi[base]) = h;
}

// ---------------- W[k][n] -> Wt[z][n][k] hi/lo bf16 (transpose + split) ----------------
__global__ __launch_bounds__(256)
void wsplit_t(const float* __restrict__ Wq, const float* __restrict__ Wk,
              const float* __restrict__ Wv, const float* __restrict__ Wo,
              ushort_t* __restrict__ Wth, ushort_t* __restrict__ Wtl)
{
    __shared__ float T[64][65];
    const int tid = threadIdx.x;
    const int z = blockIdx.z;
    const float* W = (z == 0) ? Wq : (z == 1) ? Wk : (z == 2) ? Wv : Wo;
    const int kt = blockIdx.y * 64;
    const int nt = blockIdx.x * 64;

    const int lr = (tid >> 4) * 4;
    const int lc = (tid & 15) * 4;
#pragma unroll
    for (int i = 0; i < 4; ++i) {
        float4 v = *reinterpret_cast<const float4*>(&W[(size_t)(kt + lr + i) * 1024 + nt + lc]);
        T[lr + i][lc + 0] = v.x; T[lr + i][lc + 1] = v.y;
        T[lr + i][lc + 2] = v.z; T[lr + i][lc + 3] = v.w;
    }
    __syncthreads();

    const int n = tid >> 2;
    const int kc = (tid & 3) * 16;
    us8 h[2], l[2];
#pragma unroll
    for (int u = 0; u < 2; ++u)
#pragma unroll
        for (int j = 0; j < 8; ++j) {
            float v = T[kc + u * 8 + j][n];
            ushort_t hh = f2bf(v);
            h[u][j] = hh;
            l[u][j] = f2bf(v - bf2f(hh));
        }
    ushort_t* dh = Wth + ((size_t)z * 1024 + nt + n) * 1024 + kt + kc;
    ushort_t* dl = Wtl + ((size_t)z * 1024 + nt + n) * 1024 + kt + kc;
    *reinterpret_cast<us8*>(dh)     = h[0];
    *reinterpret_cast<us8*>(dh + 8) = h[1];
    *reinterpret_cast<us8*>(dl)     = l[0];
    *reinterpret_cast<us8*>(dl + 8) = l[1];
}

// ---------------- fused QKV GEMM, PLAIN bf16, 128x128, BK=32 ----------------
__global__ __launch_bounds__(256, 3)
void gemm_qkv(const ushort_t* __restrict__ xh, const ushort_t* __restrict__ Wth,
              const float* __restrict__ bq, const float* __restrict__ bk,
              const float* __restrict__ bv,
              ushort_t* __restrict__ Qb, ushort_t* __restrict__ Kb,
              ushort_t* __restrict__ Vb, float qalpha)
{
    __shared__ ushort_t As[128 * 32], Bs[128 * 32];
    const int which = blockIdx.x >> 3;
    const int n0 = (blockIdx.x & 7) * 128;
    const int m0 = blockIdx.y * 128;
    const ushort_t* Bh = Wth + (size_t)which * 1024 * 1024;
    const float* bias = (which == 0) ? bq : (which == 1) ? bk : bv;
    ushort_t* out = (which == 0) ? Qb : (which == 1) ? Kb : Vb;
    const float alpha = (which == 0) ? qalpha : 1.0f;

    const int tid  = threadIdx.x;
    const int lane = tid & 63;
    const int w    = tid >> 6;
    const int l15  = lane & 15;
    const int g    = lane >> 4;
    const int wr   = w >> 1;
    const int wc   = w & 1;

    const int sr  = lane >> 2;
    const int scz = (lane & 3) ^ ((sr >> 1) & 3);
    const int sc  = scz * 8;
    const int j0 = w * 2, j1 = j0 + 1;

    const ushort_t* gA0 = xh + (size_t)(m0 + j0 * 16 + sr) * 1024 + sc;
    const ushort_t* gA1 = xh + (size_t)(m0 + j1 * 16 + sr) * 1024 + sc;
    const ushort_t* gB0 = Bh + (size_t)(n0 + j0 * 16 + sr) * 1024 + sc;
    const ushort_t* gB1 = Bh + (size_t)(n0 + j1 * 16 + sr) * 1024 + sc;

    const int sx  = (l15 >> 1) & 3;
    const int rd1 = (((g >> 1) + 0) ^ sx) * 8 + (g & 1) * 4;
    const int rd2 = (((g >> 1) + 2) ^ sx) * 8 + (g & 1) * 4;

    f32x4 acc[4][4];
#pragma unroll
    for (int i = 0; i < 4; ++i)
#pragma unroll
        for (int j = 0; j < 4; ++j) { acc[i][j][0] = 0.f; acc[i][j][1] = 0.f; acc[i][j][2] = 0.f; acc[i][j][3] = 0.f; }

    for (int kt = 0; kt < 32; ++kt) {
        const int k0 = kt * 32;
        if (kt) __syncthreads();
        gload16(gA0 + k0, As + j0 * 512);
        gload16(gA1 + k0, As + j1 * 512);
        gload16(gB0 + k0, Bs + j0 * 512);
        gload16(gB1 + k0, Bs + j1 * 512);
        asm volatile("s_waitcnt vmcnt(0)" ::: "memory");
        __syncthreads();

        short8 bh[4];
#pragma unroll
        for (int nb = 0; nb < 4; ++nb) {
            const int rb = (wc * 64 + nb * 16 + l15) * 32;
            union { us4 h[2]; short8 s; } u;
            u.h[0] = *reinterpret_cast<const us4*>(Bs + rb + rd1);
            u.h[1] = *reinterpret_cast<const us4*>(Bs + rb + rd2);
            bh[nb] = u.s;
        }
#pragma unroll
        for (int mb = 0; mb < 4; ++mb) {
            const int rb = (wr * 64 + mb * 16 + l15) * 32;
            union { us4 h[2]; short8 s; } ua;
            ua.h[0] = *reinterpret_cast<const us4*>(As + rb + rd1);
            ua.h[1] = *reinterpret_cast<const us4*>(As + rb + rd2);
            const short8 ah = ua.s;
#pragma unroll
            for (int nb = 0; nb < 4; ++nb)
                acc[mb][nb] = MFMA16(ah, bh[nb], acc[mb][nb], 0, 0, 0);
        }
    }

    float bvv[4];
#pragma unroll
    for (int nb = 0; nb < 4; ++nb) bvv[nb] = bias[n0 + wc * 64 + nb * 16 + l15];
#pragma unroll
    for (int mb = 0; mb < 4; ++mb)
#pragma unroll
        for (int r = 0; r < 4; ++r) {
            const size_t row = m0 + wr * 64 + mb * 16 + 4 * g + r;
#pragma unroll
            for (int nb = 0; nb < 4; ++nb) {
                const float vv = (acc[mb][nb][r] + bvv[nb]) * alpha;
                out[row * 1024 + n0 + wc * 64 + nb * 16 + l15] = f2bf(vv);
            }
        }
}

// ---------------- output GEMM bf16x3, 128x64 tiles (512 blocks, 2/CU) ----------------
__global__ __launch_bounds__(256, 2)
void gemm_o64(const ushort_t* __restrict__ Ah, const ushort_t* __restrict__ Al,
              const ushort_t* __restrict__ Bh, const ushort_t* __restrict__ Bl,
              const float* __restrict__ bias, float* __restrict__ out)
{
    __shared__ ushort_t AsH[128 * 32], AsL[128 * 32], BsH[64 * 32], BsL[64 * 32];
    const int tid  = threadIdx.x;
    const int lane = tid & 63;
    const int w    = tid >> 6;
    const int l15  = lane & 15;
    const int g    = lane >> 4;
    const int wr   = w >> 1;          // 0..1 -> 64 rows
    const int wc   = w & 1;           // 0..1 -> 32 cols
    const int n0 = blockIdx.x * 64;
    const int m0 = blockIdx.y * 128;

    const int sr  = lane >> 2;
    const int scz = (lane & 3) ^ ((sr >> 1) & 3);
    const int sc  = scz * 8;
    const int ja0 = 2 * w, ja1 = 2 * w + 1;

    const ushort_t* gAh0 = Ah + (size_t)(m0 + ja0 * 16 + sr) * 1024 + sc;
    const ushort_t* gAh1 = Ah + (size_t)(m0 + ja1 * 16 + sr) * 1024 + sc;
    const ushort_t* gAl0 = Al + (size_t)(m0 + ja0 * 16 + sr) * 1024 + sc;
    const ushort_t* gAl1 = Al + (size_t)(m0 + ja1 * 16 + sr) * 1024 + sc;
    const ushort_t* gBh0 = Bh + (size_t)(n0 + w * 16 + sr) * 1024 + sc;
    const ushort_t* gBl0 = Bl + (size_t)(n0 + w * 16 + sr) * 1024 + sc;

    const int sx  = (l15 >> 1) & 3;
    const int rd1 = (((g >> 1) + 0) ^ sx) * 8 + (g & 1) * 4;
    const int rd2 = (((g >> 1) + 2) ^ sx) * 8 + (g & 1) * 4;

    f32x4 acc[4][2];
#pragma unroll
    for (int i = 0; i < 4; ++i)
#pragma unroll
        for (int j = 0; j < 2; ++j) { acc[i][j][0] = 0.f; acc[i][j][1] = 0.f; acc[i][j][2] = 0.f; acc[i][j][3] = 0.f; }

    for (int kt = 0; kt < 32; ++kt) {
        const int k0 = kt * 32;
        if (kt) __syncthreads();
        gload16(gAh0 + k0, AsH + ja0 * 512);
        gload16(gAh1 + k0, AsH + ja1 * 512);
        gload16(gAl0 + k0, AsL + ja0 * 512);
        gload16(gAl1 + k0, AsL + ja1 * 512);
        gload16(gBh0 + k0, BsH + w * 512);
        gload16(gBl0 + k0, BsL + w * 512);
        asm volatile("s_waitcnt vmcnt(0)" ::: "memory");
        __syncthreads();

        short8 bh[2], bl[2];
#pragma unroll
        for (int nb = 0; nb < 2; ++nb) {
            const int rb = (wc * 32 + nb * 16 + l15) * 32;
            union { us4 h[2]; short8 s; } u;
            u.h[0] = *reinterpret_cast<const us4*>(BsH + rb + rd1);
            u.h[1] = *reinterpret_cast<const us4*>(BsH + rb + rd2);
            bh[nb] = u.s;
            union { us4 h[2]; short8 s; } v;
            v.h[0] = *reinterpret_cast<const us4*>(BsL + rb + rd1);
            v.h[1] = *reinterpret_cast<const us4*>(BsL + rb + rd2);
            bl[nb] = v.s;
        }
#pragma unroll
        for (int mb = 0; mb < 4; ++mb) {
            const int rb = (wr * 64 + mb * 16 + l15) * 32;
            union { us4 h[2]; short8 s; } ua;
            ua.h[0] = *reinterpret_cast<const us4*>(AsH + rb + rd1);
            ua.h[1] = *reinterpret_cast<const us4*>(AsH + rb + rd2);
            union { us4 h[2]; short8 s; } ul;
            ul.h[0] = *reinterpret_cast<const us4*>(AsL + rb + rd1);
            ul.h[1] = *reinterpret_cast<const us4*>(AsL + rb + rd2);
            const short8 ah = ua.s, al = ul.s;
#pragma unroll
            for (int nb = 0; nb < 2; ++nb) {
                acc[mb][nb] = MFMA16(ah, bh[nb], acc[mb][nb], 0, 0, 0);
                acc[mb][nb] = MFMA16(al, bh[nb], acc[mb][nb], 0, 0, 0);
                acc[mb][nb] = MFMA16(ah, bl[nb], acc[mb][nb], 0, 0, 0);
            }
        }
    }

    float bvv[2];
#pragma unroll
    for (int nb = 0; nb < 2; ++nb) bvv[nb] = bias[n0 + wc * 32 + nb * 16 + l15];
#pragma unroll
    for (int mb = 0; mb < 4; ++mb)
#pragma unroll
        for (int r = 0; r < 4; ++r) {
            const size_t row = m0 + wr * 64 + mb * 16 + 4 * g + r;
#pragma unroll
            for (int nb = 0; nb < 2; ++nb)
                out[row * 1024 + n0 + wc * 32 + nb * 16 + l15] = acc[mb][nb][r] + bvv[nb];
        }
}

// ---------------- MFMA bf16 flash attention (round-5 verified, verbatim) ----------------
__global__ __launch_bounds__(256, 2)
void attn_mfma(const ushort_t* __restrict__ Q, const ushort_t* __restrict__ K,
               const ushort_t* __restrict__ V, ushort_t* __restrict__ XHh,
               ushort_t* __restrict__ XHl)
{
    __shared__ __align__(16) ushort_t Kf[4 * 2 * 64 * 8];
    __shared__ __align__(16) ushort_t Vf[4 * 2 * 64 * 8];

    const int tid  = threadIdx.x;
    const int w    = tid >> 6;
    const int lane = tid & 63;
    const int l15  = lane & 15;
    const int g    = lane >> 4;

    const int qb = blockIdx.x;
    const int bh = blockIdx.y;
    const int b  = bh >> 4;
    const int hh = bh & 15;
    const size_t hoff = (size_t)b * S_ * E_ + (size_t)hh * S_ * D_;
    const ushort_t* Qh = Q + hoff;
    const ushort_t* Kh = K + hoff;
    const ushort_t* Vh = V + hoff;

    const int qw = qb * 128 + w * 32;

    short8 qf[2][2];
#pragma unroll
    for (int qg = 0; qg < 2; ++qg)
#pragma unroll
        for (int m = 0; m < 2; ++m) {
            const ushort_t* src = &Qh[(size_t)(qw + 16 * qg + l15) * D_ + 32 * m + 4 * g];
            us4 lo = *reinterpret_cast<const us4*>(src);
            us4 hi = *reinterpret_cast<const us4*>(src + 16);
            union { us4 h[2]; short8 s; } u;
            u.h[0] = lo; u.h[1] = hi;
            qf[qg][m] = u.s;
        }

    const int kr  = tid >> 2;
    const int kc0 = tid & 3;
    const int kkc = tid >> 4;
    const int vdc = tid & 15;
    const int vmc = kkc >> 3;
    const int vh  = (kkc >> 2) & 1;
    const int vg  = kkc & 3;
    const int vn  = vdc >> 2;

    f32x4 o[2][4];
#pragma unroll
    for (int qg = 0; qg < 2; ++qg)
#pragma unroll
        for (int n = 0; n < 4; ++n)
#pragma unroll
            for (int r = 0; r < 4; ++r) o[qg][n][r] = 0.f;

    float mrun[2] = {-1e30f, -1e30f};
    float lrun[2] = {0.f, 0.f};

    for (int kt = 0; kt < S_ / 64; ++kt) {
        us8 kreg[2];
#pragma unroll
        for (int u = 0; u < 2; ++u) {
            const int c8 = kc0 + 4 * u;
            kreg[u] = *reinterpret_cast<const us8*>(&Kh[(size_t)(kt * 64 + kr) * D_ + 8 * c8]);
        }
        us4 vreg[4];
#pragma unroll
        for (int i = 0; i < 4; ++i)
            vreg[i] = *reinterpret_cast<const us4*>(&Vh[(size_t)(kt * 64 + 4 * kkc + i) * D_ + 4 * vdc]);

        __syncthreads();

#pragma unroll
        for (int u = 0; u < 2; ++u) {
            const int c8 = kc0 + 4 * u;
            const int m = c8 >> 2;
            const int h = (c8 >> 1) & 1;
#pragma unroll
            for (int jh = 0; jh < 2; ++jh) {
                const int gk = (2 * c8 + jh) & 3;
                const int slot = gk * 16 + (kr & 15);
                us4 val;
#pragma unroll
                for (int i = 0; i < 4; ++i) val[i] = (ushort_t)kreg[u][4 * jh + i];
                *reinterpret_cast<us4*>(&Kf[((((kr >> 4) * 2 + m) * 64 + slot) * 8) + h * 4]) = val;
            }
        }
#pragma unroll
        for (int jj = 0; jj < 4; ++jj) {
            us4 val;
#pragma unroll
            for (int i = 0; i < 4; ++i) val[i] = vreg[i][jj];
            const int slot = vg * 16 + 4 * (vdc & 3) + jj;
            *reinterpret_cast<us4*>(&Vf[(((vn * 2 + vmc) * 64 + slot) * 8) + vh * 4]) = val;
        }
        __syncthreads();

        short8 kf[4][2];
#pragma unroll
        for (int kkb = 0; kkb < 4; ++kkb)
#pragma unroll
            for (int m = 0; m < 2; ++m)
                kf[kkb][m] = *reinterpret_cast<const short8*>(&Kf[((kkb * 2 + m) * 64 + lane) * 8]);

        f32x4 s[2][4];
#pragma unroll
        for (int qg = 0; qg < 2; ++qg)
#pragma unroll
            for (int kkb = 0; kkb < 4; ++kkb) {
                f32x4 z; z[0] = 0.f; z[1] = 0.f; z[2] = 0.f; z[3] = 0.f;
                z = MFMA16(kf[kkb][0], qf[qg][0], z, 0, 0, 0);
                s[qg][kkb] = MFMA16(kf[kkb][1], qf[qg][1], z, 0, 0, 0);
            }

        short8 vf[4][2];
#pragma unroll
        for (int n = 0; n < 4; ++n)
#pragma unroll
            for (int m = 0; m < 2; ++m)
                vf[n][m] = *reinterpret_cast<const short8*>(&Vf[((n * 2 + m) * 64 + lane) * 8]);

#pragma unroll
        for (int qg = 0; qg < 2; ++qg) {
            float t = s[qg][0][0];
#pragma unroll
            for (int kkb = 0; kkb < 4; ++kkb)
#pragma unroll
                for (int r = 0; r < 4; ++r) t = fmaxf(t, s[qg][kkb][r]);
            t = fmaxf(t, __shfl_xor(t, 16));
            t = fmaxf(t, __shfl_xor(t, 32));
            const float mnew = fmaxf(mrun[qg], t);
            const float corr = __builtin_amdgcn_exp2f(mrun[qg] - mnew);

            float rs = 0.f;
#pragma unroll
            for (int kkb = 0; kkb < 4; ++kkb)
#pragma unroll
                for (int r = 0; r < 4; ++r) {
                    const float p = __builtin_amdgcn_exp2f(s[qg][kkb][r] - mnew);
                    s[qg][kkb][r] = p;
                    rs += p;
                }
            rs += __shfl_xor(rs, 16);
            rs += __shfl_xor(rs, 32);
            lrun[qg] = lrun[qg] * corr + rs;
            mrun[qg] = mnew;

#pragma unroll
            for (int r = 0; r < 4; ++r) {
                const float c4 = __shfl(corr, 4 * g + r);
#pragma unroll
                for (int n = 0; n < 4; ++n) o[qg][n][r] *= c4;
            }

            short8 pa[2];
#pragma unroll
            for (int m = 0; m < 2; ++m) {
                us8 tmp;
#pragma unroll
                for (int r = 0; r < 4; ++r) {
                    tmp[r]     = f2bf(s[qg][2 * m][r]);
                    tmp[r + 4] = f2bf(s[qg][2 * m + 1][r]);
                }
                union { us8 u8; short8 s8; } cvt; cvt.u8 = tmp;
                pa[m] = cvt.s8;
            }
#pragma unroll
            for (int n = 0; n < 4; ++n) {
                o[qg][n] = MFMA16(pa[0], vf[n][0], o[qg][n], 0, 0, 0);
                o[qg][n] = MFMA16(pa[1], vf[n][1], o[qg][n], 0, 0, 0);
            }
        }
    }

#pragma unroll
    for (int qg = 0; qg < 2; ++qg) {
        const float invl = 1.f / lrun[qg];
#pragma unroll
        for (int r = 0; r < 4; ++r) {
            const float iv = __shfl(invl, 4 * g + r);
            const int row = qw + 16 * qg + 4 * g + r;
            const size_t base = ((size_t)b * S_ + row) * E_ + hh * D_ + l15;
#pragma unroll
            for (int n = 0; n < 4; ++n) {
                const float vv = o[qg][n][r] * iv;
                const ushort_t hi = f2bf(vv);
                XHh[base + 16 * n] = hi;
                XHl[base + 16 * n] = f2bf(vv - bf2f(hi));
            }
        }
    }
}

extern "C" void kernel_launch(void* const* d_in, const int* in_sizes, int n_in,
                              void* d_out, int out_size, void* d_ws, size_t ws_size,
                              hipStream_t stream) {
    (void)in_sizes; (void)n_in; (void)out_size; (void)ws_size;
    const float* x  = (const float*)d_in[0];
    const float* Wq = (const float*)d_in[1];
    const float* bq = (const float*)d_in[2];
    const float* Wk = (const float*)d_in[3];
    const float* bk = (const float*)d_in[4];
    const float* Wv = (const float*)d_in[5];
    const float* bv = (const float*)d_in[6];
    const float* Wo = (const float*)d_in[7];
    const float* bo = (const float*)d_in[8];
    float* out = (float*)d_out;

    char* ws = (char*)d_ws;
    const size_t MB8 = 8ull * 1024 * 1024;
    ushort_t* xhi = (ushort_t*)(ws);             // 8 MB, reused as XHh after QKV
    ushort_t* XHl = (ushort_t*)(ws + MB8);       // 8 MB
    ushort_t* Wth = (ushort_t*)(ws + 2 * MB8);   // 8 MB  [4][1024][1024]
    ushort_t* Wtl = (ushort_t*)(ws + 3 * MB8);   // 8 MB
    ushort_t* Qb  = (ushort_t*)(ws + 4 * MB8);   // 8 MB
    ushort_t* Kb  = (ushort_t*)(ws + 5 * MB8);   // 8 MB
    ushort_t* Vb  = (ushort_t*)(ws + 6 * MB8);   // 8 MB  (total 56 MB)
    ushort_t* XHh = xhi;

    const float qalpha = 0.125f * 1.4426950408889634f;  // 1/sqrt(D) * log2(e)

    split_x<<<dim3(2048), dim3(256), 0, stream>>>(x, xhi);
    wsplit_t<<<dim3(16, 16, 4), dim3(256), 0, stream>>>(Wq, Wk, Wv, Wo, Wth, Wtl);

    gemm_qkv<<<dim3(24, 32), dim3(256), 0, stream>>>(xhi, Wth,
                                                     bq, bk, bv, Qb, Kb, Vb, qalpha);

    attn_mfma<<<dim3(16, 32), dim3(256), 0, stream>>>(Qb, Kb, Vb, XHh, XHl);

    gemm_o64<<<dim3(16, 32), dim3(256), 0, stream>>>(XHh, XHl,
                                                     Wth + 3ull * 1024 * 1024,
                                                     Wtl + 3ull * 1024 * 1024,
                                                     bo, out);
}